// Round 12
// baseline (36.427 us; speedup 1.0000x reference)
//
#include <hip/hip_runtime.h>
#include <stdint.h>

#define NF   2344
#define ACCW 8
#define NA   38
#define TPB  512

__device__ __forceinline__ unsigned short f32_to_bf16(float f) {
    unsigned u = __float_as_uint(f);
    u += 0x7FFFu + ((u >> 16) & 1u);   // round-to-nearest-even
    return (unsigned short)(u >> 16);
}
__device__ __forceinline__ float bf16_lo(unsigned u) { return __uint_as_float(u << 16); }
__device__ __forceinline__ float bf16_hi(unsigned u) { return __uint_as_float(u & 0xFFFF0000u); }

#define KEEP2(v) asm volatile("" :: "v"(v.x), "v"(v.y))

// r11 mapping (2 thr/elem, lane h owns int2-slots {2j+h}, 32 waves/CU) with a
// 4-stage software pipeline instead of 2 monolithic phases:
//   issue B[all] -> gather B0..4 -> issue W0..4 -> gather B5..tail
//   -> issue W5..tail -> gather W0..4 -> gather W5..tail
// Global-load issue is sandwiched between LDS gather bursts so each wave mixes
// VMEM/LDS/VALU continuously; <=10 index loads (20 VGPR) in flight at any time
// (r10's single 20-load barrier and r7/r9's load-sinking both avoided: KEEP2
// per batch = one batched s_waitcnt at the gather burst head).
__global__ __launch_bounds__(TPB, 4) void nnue_fwd(
    const int* __restrict__ bfeat, const int* __restrict__ wfeat,
    const int* __restrict__ stm,
    const float* __restrict__ w1, const float* __restrict__ b1,
    const float* __restrict__ w2, const float* __restrict__ b2,
    float* __restrict__ out, int nbatch)
{
    __shared__ unsigned short tbl[NF * ACCW];   // bf16 table, 16B/row (37.5 KB)

    for (int j = threadIdx.x; j < (NF * ACCW) / 4; j += TPB) {
        float4 v = reinterpret_cast<const float4*>(w1)[j];
        unsigned lo = (unsigned)f32_to_bf16(v.x) | ((unsigned)f32_to_bf16(v.y) << 16);
        unsigned hi = (unsigned)f32_to_bf16(v.z) | ((unsigned)f32_to_bf16(v.w) << 16);
        reinterpret_cast<uint2*>(tbl)[j] = make_uint2(lo, hi);
    }
    __syncthreads();

    const int t = blockIdx.x * TPB + threadIdx.x;
    const int e = t >> 1;
    const int h = t & 1;
    if (e >= nbatch) return;

    const int* __restrict__ bp = bfeat + (long)e * NA;
    const int* __restrict__ wp = wfeat + (long)e * NA;

#define G(acc, idx) { \
        uint4 r = *reinterpret_cast<const uint4*>( \
            reinterpret_cast<const char*>(tbl) + ((unsigned)(idx) << 4)); \
        acc[0] += bf16_lo(r.x); acc[1] += bf16_hi(r.x); \
        acc[2] += bf16_lo(r.y); acc[3] += bf16_hi(r.y); \
        acc[4] += bf16_lo(r.z); acc[5] += bf16_hi(r.z); \
        acc[6] += bf16_lo(r.w); acc[7] += bf16_hi(r.w); }
#define G2(acc, v) { G(acc, v.x); G(acc, v.y); }

    float aB[8] = {0,0,0,0,0,0,0,0};
    float aW[8] = {0,0,0,0,0,0,0,0};

    // ---- stage 0: issue ALL black index loads (10 int2) + stm ----
    int2 B0 = *reinterpret_cast<const int2*>(bp +  0 + 2 * h);
    int2 B1 = *reinterpret_cast<const int2*>(bp +  4 + 2 * h);
    int2 B2 = *reinterpret_cast<const int2*>(bp +  8 + 2 * h);
    int2 B3 = *reinterpret_cast<const int2*>(bp + 12 + 2 * h);
    int2 B4 = *reinterpret_cast<const int2*>(bp + 16 + 2 * h);
    int2 B5 = *reinterpret_cast<const int2*>(bp + 20 + 2 * h);
    int2 B6 = *reinterpret_cast<const int2*>(bp + 24 + 2 * h);
    int2 B7 = *reinterpret_cast<const int2*>(bp + 28 + 2 * h);
    int2 B8 = *reinterpret_cast<const int2*>(bp + 32 + 2 * h);
    int2 BT = *reinterpret_cast<const int2*>(bp + 36);   // shared tail
    const int s = stm[e];

    // ---- stage 1: gather B[0:5] (wait covers only B0..B4) ----
    KEEP2(B0); KEEP2(B1); KEEP2(B2); KEEP2(B3); KEEP2(B4);
    G2(aB, B0); G2(aB, B1); G2(aB, B2); G2(aB, B3); G2(aB, B4);

    // ---- stage 2: issue W[0:5] while B[5:10] land ----
    int2 W0 = *reinterpret_cast<const int2*>(wp +  0 + 2 * h);
    int2 W1 = *reinterpret_cast<const int2*>(wp +  4 + 2 * h);
    int2 W2 = *reinterpret_cast<const int2*>(wp +  8 + 2 * h);
    int2 W3 = *reinterpret_cast<const int2*>(wp + 12 + 2 * h);
    int2 W4 = *reinterpret_cast<const int2*>(wp + 16 + 2 * h);
    KEEP2(B5); KEEP2(B6); KEEP2(B7); KEEP2(B8); KEEP2(BT);
    G2(aB, B5); G2(aB, B6); G2(aB, B7); G2(aB, B8);
    G(aB, h ? BT.y : BT.x);

    // ---- stage 3: issue W[5:10] while W[0:5] land ----
    int2 W5 = *reinterpret_cast<const int2*>(wp + 20 + 2 * h);
    int2 W6 = *reinterpret_cast<const int2*>(wp + 24 + 2 * h);
    int2 W7 = *reinterpret_cast<const int2*>(wp + 28 + 2 * h);
    int2 W8 = *reinterpret_cast<const int2*>(wp + 32 + 2 * h);
    int2 WT = *reinterpret_cast<const int2*>(wp + 36);
    KEEP2(W0); KEEP2(W1); KEEP2(W2); KEEP2(W3); KEEP2(W4);
    G2(aW, W0); G2(aW, W1); G2(aW, W2); G2(aW, W3); G2(aW, W4);

    // ---- stage 4: gather W[5:10] ----
    KEEP2(W5); KEEP2(W6); KEEP2(W7); KEEP2(W8); KEEP2(WT);
    G2(aW, W5); G2(aW, W6); G2(aW, W7); G2(aW, W8);
    G(aW, h ? WT.y : WT.x);
#undef G2
#undef G

    // ---- pair-combine (8 shfl): lane h finalizes color h (0=B, 1=W) ----
    float fin[8];
#pragma unroll
    for (int k = 0; k < 8; ++k) {
        float send = h ? aB[k] : aW[k];   // partial of the OTHER color
        float recv = __shfl_xor(send, 1); // peer's partial of MY color
        fin[k] = (h ? aW[k] : aB[k]) + recv + b1[k];
    }

    float dlo = 0.f, dhi = 0.f;
#pragma unroll
    for (int k = 0; k < 8; ++k) {
        float v = fminf(fmaxf(fin[k], 0.f), 1.f);
        dlo += v * w2[k];
        dhi += v * w2[8 + k];
    }

    // stm==0 -> order [black, white]; color h sits at slot 0 iff (s==0)==(h==0).
    const float m = (((s == 0)) == (h == 0)) ? dlo : dhi;
    const float o = __shfl_xor(m, 1);
    if (h == 0) out[e] = m + o + b2[0];
}

extern "C" void kernel_launch(void* const* d_in, const int* in_sizes, int n_in,
                              void* d_out, int out_size, void* d_ws, size_t ws_size,
                              hipStream_t stream) {
    const int*   bfeat = (const int*)  d_in[0];
    const int*   wfeat = (const int*)  d_in[1];
    const int*   stm   = (const int*)  d_in[2];
    const float* w1    = (const float*)d_in[3];
    const float* b1    = (const float*)d_in[4];
    const float* w2    = (const float*)d_in[5];
    const float* b2    = (const float*)d_in[6];
    float* out = (float*)d_out;

    const int nbatch  = in_sizes[2];
    const long nthread = (long)nbatch * 2;
    const int grid = (int)((nthread + TPB - 1) / TPB);
    nnue_fwd<<<grid, TPB, 0, stream>>>(bfeat, wfeat, stm, w1, b1, w2, b2, out, nbatch);
}

// Round 13
// 22.010 us; speedup vs baseline: 1.6550x; 1.6550x over previous
//
#include <hip/hip_runtime.h>
#include <stdint.h>

#define NF   2344
#define ACCW 8
#define NA   38
#define TPB  512

__device__ __forceinline__ unsigned short f32_to_bf16(float f) {
    unsigned u = __float_as_uint(f);
    u += 0x7FFFu + ((u >> 16) & 1u);   // round-to-nearest-even
    return (unsigned short)(u >> 16);
}
__device__ __forceinline__ float bf16_lo(unsigned u) { return __uint_as_float(u << 16); }
__device__ __forceinline__ float bf16_hi(unsigned u) { return __uint_as_float(u & 0xFFFF0000u); }

// r11 structure (proven best codegen shape: per-color q[9] batch -> 19-gather
// burst, 2 thr/elem, 32 waves/CU) + WAVE-PARITY PHASE STAGGER: even waves
// process black-first, odd waves white-first, so at any instant ~half the
// CU's waves are in a VMEM-load burst and half in an LDS-gather burst
// (r11's phases were CU-synchronized -> pipes alternated idle/saturated).
// Zero extra per-thread state: cannot trigger the VGPR-minimizer failure
// mode that killed r7/r9/r12.
__global__ __launch_bounds__(TPB, 4) void nnue_fwd(
    const int* __restrict__ bfeat, const int* __restrict__ wfeat,
    const int* __restrict__ stm,
    const float* __restrict__ w1, const float* __restrict__ b1,
    const float* __restrict__ w2, const float* __restrict__ b2,
    float* __restrict__ out, int nbatch)
{
    __shared__ unsigned short tbl[NF * ACCW];   // bf16 table, 16B/row (37.5 KB)

    for (int j = threadIdx.x; j < (NF * ACCW) / 4; j += TPB) {
        float4 v = reinterpret_cast<const float4*>(w1)[j];
        unsigned lo = (unsigned)f32_to_bf16(v.x) | ((unsigned)f32_to_bf16(v.y) << 16);
        unsigned hi = (unsigned)f32_to_bf16(v.z) | ((unsigned)f32_to_bf16(v.w) << 16);
        reinterpret_cast<uint2*>(tbl)[j] = make_uint2(lo, hi);
    }
    __syncthreads();

    const int t = blockIdx.x * TPB + threadIdx.x;
    const int e = t >> 1;
    const int h = t & 1;
    if (e >= nbatch) return;

    const int p = (threadIdx.x >> 6) & 1;        // wave parity (uniform/wave)
    const int* __restrict__ bp = bfeat + (long)e * NA;
    const int* __restrict__ wp = wfeat + (long)e * NA;
    const int* __restrict__ pA = p ? wp : bp;    // first-phase color = p
    const int* __restrict__ pB = p ? bp : wp;    // second-phase color = 1-p

#define G(acc, idx) { \
        uint4 r = *reinterpret_cast<const uint4*>( \
            reinterpret_cast<const char*>(tbl) + ((unsigned)(idx) << 4)); \
        acc[0] += bf16_lo(r.x); acc[1] += bf16_hi(r.x); \
        acc[2] += bf16_lo(r.y); acc[3] += bf16_hi(r.y); \
        acc[4] += bf16_lo(r.z); acc[5] += bf16_hi(r.z); \
        acc[6] += bf16_lo(r.w); acc[7] += bf16_hi(r.w); }

    float accA[8] = {0,0,0,0,0,0,0,0};   // color p
    float accC[8] = {0,0,0,0,0,0,0,0};   // color 1-p
    int s;

    // ---- phase A: color p (stm rides in the same load batch) ----
    {
        int2 q[9];
#pragma unroll
        for (int j = 0; j < 9; ++j)
            q[j] = *reinterpret_cast<const int2*>(pA + 4 * j + 2 * h);
        const int2 qt = *reinterpret_cast<const int2*>(pA + 36);  // shared slot
        s = stm[e];
#pragma unroll
        for (int j = 0; j < 9; ++j) { G(accA, q[j].x); G(accA, q[j].y); }
        G(accA, h ? qt.y : qt.x);
    }

    asm volatile("" ::: "memory");   // keep the two phases' live sets separate

    // ---- phase B: color 1-p ----
    {
        int2 q[9];
#pragma unroll
        for (int j = 0; j < 9; ++j)
            q[j] = *reinterpret_cast<const int2*>(pB + 4 * j + 2 * h);
        const int2 qt = *reinterpret_cast<const int2*>(pB + 36);
#pragma unroll
        for (int j = 0; j < 9; ++j) { G(accC, q[j].x); G(accC, q[j].y); }
        G(accC, h ? qt.y : qt.x);
    }
#undef G

    // ---- pair-combine (8 shfl): lane h finalizes color h ----
    // my partial of color h: (h==p) ? accA : accC ; send the other one.
    float fin[8];
#pragma unroll
    for (int k = 0; k < 8; ++k) {
        float mineK = (h == p) ? accA[k] : accC[k];
        float send  = (h == p) ? accC[k] : accA[k];
        float recv  = __shfl_xor(send, 1);   // peer's partial of MY color
        fin[k] = mineK + recv + b1[k];
    }

    float dlo = 0.f, dhi = 0.f;
#pragma unroll
    for (int k = 0; k < 8; ++k) {
        float v = fminf(fmaxf(fin[k], 0.f), 1.f);
        dlo += v * w2[k];
        dhi += v * w2[8 + k];
    }

    // stm==0 -> order [black, white]; color h sits at slot 0 iff (s==0)==(h==0).
    const float m = (((s == 0)) == (h == 0)) ? dlo : dhi;
    const float o = __shfl_xor(m, 1);
    if (h == 0) out[e] = m + o + b2[0];
}

extern "C" void kernel_launch(void* const* d_in, const int* in_sizes, int n_in,
                              void* d_out, int out_size, void* d_ws, size_t ws_size,
                              hipStream_t stream) {
    const int*   bfeat = (const int*)  d_in[0];
    const int*   wfeat = (const int*)  d_in[1];
    const int*   stm   = (const int*)  d_in[2];
    const float* w1    = (const float*)d_in[3];
    const float* b1    = (const float*)d_in[4];
    const float* w2    = (const float*)d_in[5];
    const float* b2    = (const float*)d_in[6];
    float* out = (float*)d_out;

    const int nbatch  = in_sizes[2];
    const long nthread = (long)nbatch * 2;
    const int grid = (int)((nthread + TPB - 1) / TPB);
    nnue_fwd<<<grid, TPB, 0, stream>>>(bfeat, wfeat, stm, w1, b1, w2, b2, out, nbatch);
}